// Round 2
// baseline (304.395 us; speedup 1.0000x reference)
//
#include <hip/hip_runtime.h>
#include <math.h>

namespace {

typedef _Float16 half8 __attribute__((ext_vector_type(8)));
typedef float floatx4 __attribute__((ext_vector_type(4)));

constexpr int kS   = 1024;
constexpr int kD   = 64;
constexpr int kPad = 72;   // 144 B row stride: 16B-aligned, banks at phase floor
constexpr float kLog2e = 1.4426950408889634f;
constexpr float kThr   = 8.0f;  // defer-rescale threshold (log2 space): p <= 2^8

union H4 { _Float16 h[4]; uint2 u2; };

__device__ __forceinline__ float fast_exp2(float x) {
#if __has_builtin(__builtin_amdgcn_exp2f)
  return __builtin_amdgcn_exp2f(x);
#else
  return exp2f(x);
#endif
}

__device__ __forceinline__ float fast_rcp(float x) {
#if __has_builtin(__builtin_amdgcn_rcpf)
  return __builtin_amdgcn_rcpf(x);
#else
  return 1.0f / x;
#endif
}

__global__ __launch_bounds__(256, 4)
void fa_mfma_kernel(const float* __restrict__ qg, const float* __restrict__ kg,
                    const float* __restrict__ vg, float* __restrict__ og) {
  __shared__ __align__(16) _Float16 sK [64][kPad];   // K tile [key][d]
  __shared__ __align__(16) _Float16 sVt[64][kPad];   // V^T tile [d][key]
  __shared__ __align__(16) _Float16 sP [128][kPad];  // P [qrow(block)][key]

  const int tid  = threadIdx.x;
  const int lane = tid & 63;
  const int w    = __builtin_amdgcn_readfirstlane(tid >> 6);
  const int quad = lane >> 4;
  const int r    = lane & 15;

  // XCD swizzle: all 8 q-tiles of a batch -> same XCD (i%8 dispatch heuristic).
  const int blk = blockIdx.x;
  const int s   = blk >> 3;
  const int b   = (blk & 7) + 8 * (s & 15);  // batch 0..127
  const int qbase = (s >> 4) * 128;          // q-tile 0..7

  const float* qb = qg + (size_t)b * kS * kD;
  const float* kb = kg + (size_t)b * kS * kD;
  const float* vb = vg + (size_t)b * kS * kD;
  float*       ob = og + (size_t)b * kS * kD;

  // ---- Q fragments direct from global: hi/lo f16 split, pre-scaled log2e ----
  // B-operand layout: n = lane&15 -> qrow-in-group, k = quad*8+j -> dim.
  half8 fqh[2][2], fql[2][2];  // [ntq][ks]
#pragma unroll
  for (int ntq = 0; ntq < 2; ++ntq)
#pragma unroll
    for (int ks = 0; ks < 2; ++ks) {
      const float* src =
          qb + (size_t)(qbase + w * 32 + ntq * 16 + r) * kD + ks * 32 + quad * 8;
      float4 a = ((const float4*)src)[0];
      float4 c = ((const float4*)src)[1];
      float f[8] = {a.x, a.y, a.z, a.w, c.x, c.y, c.z, c.w};
#pragma unroll
      for (int j = 0; j < 8; ++j) {
        float x = f[j] * kLog2e;
        _Float16 h = (_Float16)x;
        fqh[ntq][ks][j] = h;
        fql[ntq][ks][j] = (_Float16)(x - (float)h);
      }
    }

  // Softmax state: lane's 2 q-rows are ntq*16 + r (replicated across quads).
  float m_i[2] = {-INFINITY, -INFINITY}, l_i[2] = {0.f, 0.f};
  // O accum: D[m=qrow][n=dim]; [mtq][nd], row=mtq*16+quad*4+reg, col=nd*16+r.
  floatx4 O[2][4];
#pragma unroll
  for (int a = 0; a < 2; ++a)
#pragma unroll
    for (int c = 0; c < 4; ++c) O[a][c] = floatx4{0.f, 0.f, 0.f, 0.f};

  // K/V prefetch registers (one tile ahead).
  const int krow = tid >> 2, kc0 = (tid & 3) * 16;   // K row-major copy
  const int vkey4 = (tid & 15) * 4;                  // V: 4 consecutive keys
  const int vd0   = (tid >> 4) * 4;                  //    x 4 dims sub-tile
  float4 kbuf[4], vbuf[4];
  {
    const float4* ksrc = (const float4*)(kb + (size_t)krow * kD + kc0);
#pragma unroll
    for (int g = 0; g < 4; ++g) kbuf[g] = ksrc[g];
#pragma unroll
    for (int kk = 0; kk < 4; ++kk)
      vbuf[kk] = *(const float4*)(vb + (size_t)(vkey4 + kk) * kD + vd0);
  }

  for (int kt = 0; kt < kS / 64; ++kt) {
    __syncthreads();  // previous tile's compute done; LDS K/V reusable
    // ---- stage K (row-major f16) ----
#pragma unroll
    for (int g = 0; g < 4; ++g) {
      float t[4] = {kbuf[g].x, kbuf[g].y, kbuf[g].z, kbuf[g].w};
      H4 hk;
#pragma unroll
      for (int j = 0; j < 4; ++j) hk.h[j] = (_Float16)t[j];
      *(uint2*)&sK[krow][kc0 + g * 4] = hk.u2;
    }
    // ---- stage V transposed via in-register 4x4 sub-transpose ----
    {
      float tv[4][4];
#pragma unroll
      for (int kk = 0; kk < 4; ++kk) {
        tv[kk][0] = vbuf[kk].x; tv[kk][1] = vbuf[kk].y;
        tv[kk][2] = vbuf[kk].z; tv[kk][3] = vbuf[kk].w;
      }
#pragma unroll
      for (int j = 0; j < 4; ++j) {
        H4 hv;
#pragma unroll
        for (int kk = 0; kk < 4; ++kk) hv.h[kk] = (_Float16)tv[kk][j];
        *(uint2*)&sVt[vd0 + j][vkey4] = hv.u2;
      }
    }
    // ---- prefetch next tile ----
    {
      const int ktn = (kt + 1) & 15;
      const float4* ksrc =
          (const float4*)(kb + (size_t)(ktn * 64 + krow) * kD + kc0);
#pragma unroll
      for (int g = 0; g < 4; ++g) kbuf[g] = ksrc[g];
#pragma unroll
      for (int kk = 0; kk < 4; ++kk)
        vbuf[kk] =
            *(const float4*)(vb + (size_t)(ktn * 64 + vkey4 + kk) * kD + vd0);
    }
    __syncthreads();

    // ---- S^T = K·Q^T: per mt one pair of fk reads feeds BOTH q-groups ----
    floatx4 S[2][4];  // [ntq][mt]; score(key=mt*16+quad*4+reg, qrow=ntq*16+r)
    __builtin_amdgcn_s_setprio(1);
#pragma unroll
    for (int mt = 0; mt < 4; ++mt) {
      half8 fk0 = *(const half8*)&sK[mt * 16 + r][0 * 32 + quad * 8];
      half8 fk1 = *(const half8*)&sK[mt * 16 + r][1 * 32 + quad * 8];
#pragma unroll
      for (int ntq = 0; ntq < 2; ++ntq) {
        floatx4 ah = {0.f, 0.f, 0.f, 0.f}, al = {0.f, 0.f, 0.f, 0.f};
        ah = __builtin_amdgcn_mfma_f32_16x16x32_f16(fk0, fqh[ntq][0], ah, 0, 0, 0);
        ah = __builtin_amdgcn_mfma_f32_16x16x32_f16(fk1, fqh[ntq][1], ah, 0, 0, 0);
        al = __builtin_amdgcn_mfma_f32_16x16x32_f16(fk0, fql[ntq][0], al, 0, 0, 0);
        al = __builtin_amdgcn_mfma_f32_16x16x32_f16(fk1, fql[ntq][1], al, 0, 0, 0);
        S[ntq][mt] = ah + al;
      }
    }
    __builtin_amdgcn_s_setprio(0);

    // ---- online softmax with deferred rescale (T13) ----
    float tm[2];
#pragma unroll
    for (int ntq = 0; ntq < 2; ++ntq) {
      float t = -INFINITY;
#pragma unroll
      for (int mt = 0; mt < 4; ++mt)
#pragma unroll
        for (int j = 0; j < 4; ++j) t = fmaxf(t, S[ntq][mt][j]);
      t = fmaxf(t, __shfl_xor(t, 16, 64));
      t = fmaxf(t, __shfl_xor(t, 32, 64));
      tm[ntq] = t;
    }
    const unsigned long long need =
        __ballot(tm[0] > m_i[0] + kThr || tm[1] > m_i[1] + kThr);
    if (need) {
      float alpha[2];
#pragma unroll
      for (int ntq = 0; ntq < 2; ++ntq) {
        const float mn = fmaxf(m_i[ntq], tm[ntq]);
        alpha[ntq] = fast_exp2(m_i[ntq] - mn);  // first tile: exp2(-inf)=0
        m_i[ntq] = mn;
        l_i[ntq] *= alpha[ntq];
      }
      // rescale O by alpha (row of O[mtq] = mtq*16 + quad*4 + j)
#pragma unroll
      for (int mtq = 0; mtq < 2; ++mtq)
#pragma unroll
        for (int j = 0; j < 4; ++j) {
          const float a = __shfl(alpha[mtq], quad * 4 + j, 64);
#pragma unroll
          for (int nd = 0; nd < 4; ++nd) O[mtq][nd][j] *= a;
        }
    }
    // P = exp2(S - m) with (possibly stale) m; pack to f16; accumulate l.
#pragma unroll
    for (int ntq = 0; ntq < 2; ++ntq) {
      float rs = 0.f;
#pragma unroll
      for (int mt = 0; mt < 4; ++mt) {
        H4 hp;
#pragma unroll
        for (int j = 0; j < 4; ++j) {
          float pj = fast_exp2(S[ntq][mt][j] - m_i[ntq]);
          rs += pj;
          hp.h[j] = (_Float16)pj;
        }
        *(uint2*)&sP[w * 32 + ntq * 16 + r][mt * 16 + quad * 4] = hp.u2;
      }
      rs += __shfl_xor(rs, 16, 64);
      rs += __shfl_xor(rs, 32, 64);
      l_i[ntq] += rs;
    }

    // ---- O += P·V: fv reads shared across both q-row groups ----
    __builtin_amdgcn_s_setprio(1);
#pragma unroll
    for (int ks = 0; ks < 2; ++ks) {
      half8 fp0 = *(const half8*)&sP[w * 32 + 0 * 16 + r][ks * 32 + quad * 8];
      half8 fp1 = *(const half8*)&sP[w * 32 + 1 * 16 + r][ks * 32 + quad * 8];
#pragma unroll
      for (int nd = 0; nd < 4; ++nd) {
        half8 fv = *(const half8*)&sVt[nd * 16 + r][ks * 32 + quad * 8];
        O[0][nd] = __builtin_amdgcn_mfma_f32_16x16x32_f16(fp0, fv, O[0][nd], 0, 0, 0);
        O[1][nd] = __builtin_amdgcn_mfma_f32_16x16x32_f16(fp1, fv, O[1][nd], 0, 0, 0);
      }
    }
    __builtin_amdgcn_s_setprio(0);
  }

  // ---- epilogue: out[qrow][dim] = O / l ----
#pragma unroll
  for (int mtq = 0; mtq < 2; ++mtq)
#pragma unroll
    for (int j = 0; j < 4; ++j) {
      const float lrow = __shfl(l_i[mtq], quad * 4 + j, 64);
      const float linv = fast_rcp(lrow);
      float* dst =
          ob + (size_t)(qbase + w * 32 + mtq * 16 + quad * 4 + j) * kD + r;
#pragma unroll
      for (int nd = 0; nd < 4; ++nd) dst[nd * 16] = O[mtq][nd][j] * linv;
    }
}

}  // namespace

extern "C" void kernel_launch(void* const* d_in, const int* in_sizes, int n_in,
                              void* d_out, int out_size, void* d_ws, size_t ws_size,
                              hipStream_t stream) {
  const float* q = (const float*)d_in[0];
  const float* k = (const float*)d_in[1];
  const float* v = (const float*)d_in[2];
  float* out = (float*)d_out;

  fa_mfma_kernel<<<dim3(1024), 256, 0, stream>>>(q, k, v, out);
}

// Round 3
// 195.187 us; speedup vs baseline: 1.5595x; 1.5595x over previous
//
#include <hip/hip_runtime.h>
#include <math.h>

namespace {

typedef _Float16 half8 __attribute__((ext_vector_type(8)));
typedef float floatx4 __attribute__((ext_vector_type(4)));

constexpr int kS   = 1024;
constexpr int kD   = 64;
constexpr int kPad = 72;   // 144 B row stride: 16B-aligned, banks at phase floor
constexpr float kLog2e = 1.4426950408889634f;
constexpr float kThr   = 8.0f;  // defer-rescale threshold (log2 space): p <= 2^8

union H4 { _Float16 h[4]; uint2 u2; };

__device__ __forceinline__ float fast_exp2(float x) {
#if __has_builtin(__builtin_amdgcn_exp2f)
  return __builtin_amdgcn_exp2f(x);
#else
  return exp2f(x);
#endif
}

__device__ __forceinline__ float fast_rcp(float x) {
#if __has_builtin(__builtin_amdgcn_rcpf)
  return __builtin_amdgcn_rcpf(x);
#else
  return 1.0f / x;
#endif
}

// 3 blocks/CU: the live set (Q frags 32 + O 32 + K/V prefetch 32 + S 32 + addr)
// needs ~160 regs; forcing 4 blocks/CU (128-reg budget) spills ~35 regs/thread
// -> +560 MB/dispatch scratch traffic, dur 120->213 us (measured round 2).
__global__ __launch_bounds__(256, 3)
void fa_mfma_kernel(const float* __restrict__ qg, const float* __restrict__ kg,
                    const float* __restrict__ vg, float* __restrict__ og) {
  __shared__ __align__(16) _Float16 sK [64][kPad];   // K tile [key][d]
  __shared__ __align__(16) _Float16 sVt[64][kPad];   // V^T tile [d][key]
  __shared__ __align__(16) _Float16 sP [128][kPad];  // P [qrow(block)][key]

  const int tid  = threadIdx.x;
  const int lane = tid & 63;
  const int w    = __builtin_amdgcn_readfirstlane(tid >> 6);
  const int quad = lane >> 4;
  const int r    = lane & 15;

  // XCD swizzle: all 8 q-tiles of a batch -> same XCD (i%8 dispatch heuristic).
  const int blk = blockIdx.x;
  const int s   = blk >> 3;
  const int b   = (blk & 7) + 8 * (s & 15);  // batch 0..127
  const int qbase = (s >> 4) * 128;          // q-tile 0..7

  const float* qb = qg + (size_t)b * kS * kD;
  const float* kb = kg + (size_t)b * kS * kD;
  const float* vb = vg + (size_t)b * kS * kD;
  float*       ob = og + (size_t)b * kS * kD;

  // ---- Q fragments direct from global: hi/lo f16 split, pre-scaled log2e ----
  // B-operand layout: n = lane&15 -> qrow-in-group, k = quad*8+j -> dim.
  half8 fqh[2][2], fql[2][2];  // [ntq][ks]
#pragma unroll
  for (int ntq = 0; ntq < 2; ++ntq)
#pragma unroll
    for (int ks = 0; ks < 2; ++ks) {
      const float* src =
          qb + (size_t)(qbase + w * 32 + ntq * 16 + r) * kD + ks * 32 + quad * 8;
      float4 a = ((const float4*)src)[0];
      float4 c = ((const float4*)src)[1];
      float f[8] = {a.x, a.y, a.z, a.w, c.x, c.y, c.z, c.w};
#pragma unroll
      for (int j = 0; j < 8; ++j) {
        float x = f[j] * kLog2e;
        _Float16 h = (_Float16)x;
        fqh[ntq][ks][j] = h;
        fql[ntq][ks][j] = (_Float16)(x - (float)h);
      }
    }

  // Softmax state: lane's 2 q-rows are ntq*16 + r (replicated across quads).
  float m_i[2] = {-INFINITY, -INFINITY}, l_i[2] = {0.f, 0.f};
  // O accum: D[m=qrow][n=dim]; [mtq][nd], row=mtq*16+quad*4+reg, col=nd*16+r.
  floatx4 O[2][4];
#pragma unroll
  for (int a = 0; a < 2; ++a)
#pragma unroll
    for (int c = 0; c < 4; ++c) O[a][c] = floatx4{0.f, 0.f, 0.f, 0.f};

  // K/V prefetch registers (one tile ahead).
  const int krow = tid >> 2, kc0 = (tid & 3) * 16;   // K row-major copy
  const int vkey4 = (tid & 15) * 4;                  // V: 4 consecutive keys
  const int vd0   = (tid >> 4) * 4;                  //    x 4 dims sub-tile
  float4 kbuf[4], vbuf[4];
  {
    const float4* ksrc = (const float4*)(kb + (size_t)krow * kD + kc0);
#pragma unroll
    for (int g = 0; g < 4; ++g) kbuf[g] = ksrc[g];
#pragma unroll
    for (int kk = 0; kk < 4; ++kk)
      vbuf[kk] = *(const float4*)(vb + (size_t)(vkey4 + kk) * kD + vd0);
  }

  for (int kt = 0; kt < kS / 64; ++kt) {
    __syncthreads();  // previous tile's compute done; LDS K/V reusable
    // ---- stage K (row-major f16) ----
#pragma unroll
    for (int g = 0; g < 4; ++g) {
      float t[4] = {kbuf[g].x, kbuf[g].y, kbuf[g].z, kbuf[g].w};
      H4 hk;
#pragma unroll
      for (int j = 0; j < 4; ++j) hk.h[j] = (_Float16)t[j];
      *(uint2*)&sK[krow][kc0 + g * 4] = hk.u2;
    }
    // ---- stage V transposed via in-register 4x4 sub-transpose ----
    {
      float tv[4][4];
#pragma unroll
      for (int kk = 0; kk < 4; ++kk) {
        tv[kk][0] = vbuf[kk].x; tv[kk][1] = vbuf[kk].y;
        tv[kk][2] = vbuf[kk].z; tv[kk][3] = vbuf[kk].w;
      }
#pragma unroll
      for (int j = 0; j < 4; ++j) {
        H4 hv;
#pragma unroll
        for (int kk = 0; kk < 4; ++kk) hv.h[kk] = (_Float16)tv[kk][j];
        *(uint2*)&sVt[vd0 + j][vkey4] = hv.u2;
      }
    }
    // ---- prefetch next tile ----
    {
      const int ktn = (kt + 1) & 15;
      const float4* ksrc =
          (const float4*)(kb + (size_t)(ktn * 64 + krow) * kD + kc0);
#pragma unroll
      for (int g = 0; g < 4; ++g) kbuf[g] = ksrc[g];
#pragma unroll
      for (int kk = 0; kk < 4; ++kk)
        vbuf[kk] =
            *(const float4*)(vb + (size_t)(ktn * 64 + vkey4 + kk) * kD + vd0);
    }
    __syncthreads();

    // ---- S^T = K·Q^T: per mt one pair of fk reads feeds BOTH q-groups ----
    floatx4 S[2][4];  // [ntq][mt]; score(key=mt*16+quad*4+reg, qrow=ntq*16+r)
    __builtin_amdgcn_s_setprio(1);
#pragma unroll
    for (int mt = 0; mt < 4; ++mt) {
      half8 fk0 = *(const half8*)&sK[mt * 16 + r][0 * 32 + quad * 8];
      half8 fk1 = *(const half8*)&sK[mt * 16 + r][1 * 32 + quad * 8];
#pragma unroll
      for (int ntq = 0; ntq < 2; ++ntq) {
        floatx4 ah = {0.f, 0.f, 0.f, 0.f}, al = {0.f, 0.f, 0.f, 0.f};
        ah = __builtin_amdgcn_mfma_f32_16x16x32_f16(fk0, fqh[ntq][0], ah, 0, 0, 0);
        ah = __builtin_amdgcn_mfma_f32_16x16x32_f16(fk1, fqh[ntq][1], ah, 0, 0, 0);
        al = __builtin_amdgcn_mfma_f32_16x16x32_f16(fk0, fql[ntq][0], al, 0, 0, 0);
        al = __builtin_amdgcn_mfma_f32_16x16x32_f16(fk1, fql[ntq][1], al, 0, 0, 0);
        S[ntq][mt] = ah + al;
      }
    }
    __builtin_amdgcn_s_setprio(0);

    // ---- online softmax with deferred rescale (T13) ----
    float tm[2];
#pragma unroll
    for (int ntq = 0; ntq < 2; ++ntq) {
      float t = -INFINITY;
#pragma unroll
      for (int mt = 0; mt < 4; ++mt)
#pragma unroll
        for (int j = 0; j < 4; ++j) t = fmaxf(t, S[ntq][mt][j]);
      t = fmaxf(t, __shfl_xor(t, 16, 64));
      t = fmaxf(t, __shfl_xor(t, 32, 64));
      tm[ntq] = t;
    }
    const unsigned long long need =
        __ballot(tm[0] > m_i[0] + kThr || tm[1] > m_i[1] + kThr);
    if (need) {
      float alpha[2];
#pragma unroll
      for (int ntq = 0; ntq < 2; ++ntq) {
        const float mn = fmaxf(m_i[ntq], tm[ntq]);
        alpha[ntq] = fast_exp2(m_i[ntq] - mn);  // first tile: exp2(-inf)=0
        m_i[ntq] = mn;
        l_i[ntq] *= alpha[ntq];
      }
      // rescale O by alpha (row of O[mtq] = mtq*16 + quad*4 + j)
#pragma unroll
      for (int mtq = 0; mtq < 2; ++mtq)
#pragma unroll
        for (int j = 0; j < 4; ++j) {
          const float a = __shfl(alpha[mtq], quad * 4 + j, 64);
#pragma unroll
          for (int nd = 0; nd < 4; ++nd) O[mtq][nd][j] *= a;
        }
    }
    // P = exp2(S - m) with (possibly stale) m; pack to f16; accumulate l.
#pragma unroll
    for (int ntq = 0; ntq < 2; ++ntq) {
      float rs = 0.f;
#pragma unroll
      for (int mt = 0; mt < 4; ++mt) {
        H4 hp;
#pragma unroll
        for (int j = 0; j < 4; ++j) {
          float pj = fast_exp2(S[ntq][mt][j] - m_i[ntq]);
          rs += pj;
          hp.h[j] = (_Float16)pj;
        }
        *(uint2*)&sP[w * 32 + ntq * 16 + r][mt * 16 + quad * 4] = hp.u2;
      }
      rs += __shfl_xor(rs, 16, 64);
      rs += __shfl_xor(rs, 32, 64);
      l_i[ntq] += rs;
    }

    // ---- O += P·V: fv reads shared across both q-row groups ----
    __builtin_amdgcn_s_setprio(1);
#pragma unroll
    for (int ks = 0; ks < 2; ++ks) {
      half8 fp0 = *(const half8*)&sP[w * 32 + 0 * 16 + r][ks * 32 + quad * 8];
      half8 fp1 = *(const half8*)&sP[w * 32 + 1 * 16 + r][ks * 32 + quad * 8];
#pragma unroll
      for (int nd = 0; nd < 4; ++nd) {
        half8 fv = *(const half8*)&sVt[nd * 16 + r][ks * 32 + quad * 8];
        O[0][nd] = __builtin_amdgcn_mfma_f32_16x16x32_f16(fp0, fv, O[0][nd], 0, 0, 0);
        O[1][nd] = __builtin_amdgcn_mfma_f32_16x16x32_f16(fp1, fv, O[1][nd], 0, 0, 0);
      }
    }
    __builtin_amdgcn_s_setprio(0);
  }

  // ---- epilogue: out[qrow][dim] = O / l ----
#pragma unroll
  for (int mtq = 0; mtq < 2; ++mtq)
#pragma unroll
    for (int j = 0; j < 4; ++j) {
      const float lrow = __shfl(l_i[mtq], quad * 4 + j, 64);
      const float linv = fast_rcp(lrow);
      float* dst =
          ob + (size_t)(qbase + w * 32 + mtq * 16 + quad * 4 + j) * kD + r;
#pragma unroll
      for (int nd = 0; nd < 4; ++nd) dst[nd * 16] = O[mtq][nd][j] * linv;
    }
}

}  // namespace

extern "C" void kernel_launch(void* const* d_in, const int* in_sizes, int n_in,
                              void* d_out, int out_size, void* d_ws, size_t ws_size,
                              hipStream_t stream) {
  const float* q = (const float*)d_in[0];
  const float* k = (const float*)d_in[1];
  const float* v = (const float*)d_in[2];
  float* out = (float*)d_out;

  fa_mfma_kernel<<<dim3(1024), 256, 0, stream>>>(q, k, v, out);
}

// Round 4
// 172.697 us; speedup vs baseline: 1.7626x; 1.1302x over previous
//
#include <hip/hip_runtime.h>
#include <math.h>

namespace {

typedef _Float16 half8 __attribute__((ext_vector_type(8)));
typedef float floatx4 __attribute__((ext_vector_type(4)));

constexpr int kS   = 1024;
constexpr int kD   = 64;
constexpr int kPad = 72;   // 144 B row stride: 16B-aligned, banks at phase floor
constexpr float kLog2e = 1.4426950408889634f;
constexpr float kThr   = 8.0f;  // defer-rescale threshold (log2 space): p <= 2^8

union H4 { _Float16 h[4]; uint2 u2; };

__device__ __forceinline__ float fast_exp2(float x) {
#if __has_builtin(__builtin_amdgcn_exp2f)
  return __builtin_amdgcn_exp2f(x);
#else
  return exp2f(x);
#endif
}

__device__ __forceinline__ float fast_rcp(float x) {
#if __has_builtin(__builtin_amdgcn_rcpf)
  return __builtin_amdgcn_rcpf(x);
#else
  return 1.0f / x;
#endif
}

// 64 q-rows/wave, 256 rows/block, grid 512: 2 blocks/CU -> whole grid resident
// in ONE round (no tail; round-3 structure had 1024 blocks @3/CU = 1.33 rounds).
// Live set ~220 VGPR (fq 64 + O 64 + prefetch 32 + S 32 + state/addr) needs the
// 256-reg budget: (256,2). (256,3)'s 170-reg budget would spill (round-2 lesson).
__global__ __launch_bounds__(256, 2)
void fa_mfma_kernel(const float* __restrict__ qg, const float* __restrict__ kg,
                    const float* __restrict__ vg, float* __restrict__ og) {
  __shared__ __align__(16) _Float16 sK [64][kPad];   // K tile [key][d]
  __shared__ __align__(16) _Float16 sVt[64][kPad];   // V^T tile [d][key]
  __shared__ __align__(16) _Float16 sP [256][kPad];  // P [qrow(block)][key]

  const int tid  = threadIdx.x;
  const int lane = tid & 63;
  const int w    = __builtin_amdgcn_readfirstlane(tid >> 6);
  const int quad = lane >> 4;
  const int r    = lane & 15;

  // XCD swizzle for 512 blocks: batch b's 4 q-tile blocks -> same XCD (i%8).
  const int blk = blockIdx.x;
  const int b     = (blk & 7) + 8 * (blk >> 5);  // batch 0..127
  const int qbase = ((blk >> 3) & 3) * 256;      // q-tile 0..3 (256 rows each)

  const float* qb = qg + (size_t)b * kS * kD;
  const float* kb = kg + (size_t)b * kS * kD;
  const float* vb = vg + (size_t)b * kS * kD;
  float*       ob = og + (size_t)b * kS * kD;

  // ---- Q fragments direct from global: hi/lo f16 split, pre-scaled log2e ----
  // B-operand layout: n = lane&15 -> qrow-in-group, k = quad*8+j -> dim.
  half8 fqh[4][2], fql[4][2];  // [ntq][ks]
#pragma unroll
  for (int ntq = 0; ntq < 4; ++ntq)
#pragma unroll
    for (int ks = 0; ks < 2; ++ks) {
      const float* src =
          qb + (size_t)(qbase + w * 64 + ntq * 16 + r) * kD + ks * 32 + quad * 8;
      float4 a = ((const float4*)src)[0];
      float4 c = ((const float4*)src)[1];
      float f[8] = {a.x, a.y, a.z, a.w, c.x, c.y, c.z, c.w};
#pragma unroll
      for (int j = 0; j < 8; ++j) {
        float x = f[j] * kLog2e;
        _Float16 h = (_Float16)x;
        fqh[ntq][ks][j] = h;
        fql[ntq][ks][j] = (_Float16)(x - (float)h);
      }
    }

  // Softmax state: lane's 4 q-rows are ntq*16 + r (replicated across quads).
  float m_i[4] = {-INFINITY, -INFINITY, -INFINITY, -INFINITY};
  float l_i[4] = {0.f, 0.f, 0.f, 0.f};
  // O accum: D[m=qrow][n=dim]; [mtq][nd], row=mtq*16+quad*4+reg, col=nd*16+r.
  floatx4 O[4][4];
#pragma unroll
  for (int a = 0; a < 4; ++a)
#pragma unroll
    for (int c = 0; c < 4; ++c) O[a][c] = floatx4{0.f, 0.f, 0.f, 0.f};

  // K/V prefetch registers (one tile ahead).
  const int krow = tid >> 2, kc0 = (tid & 3) * 16;   // K row-major copy
  const int vkey4 = (tid & 15) * 4;                  // V: 4 consecutive keys
  const int vd0   = (tid >> 4) * 4;                  //    x 4 dims sub-tile
  float4 kbuf[4], vbuf[4];
  {
    const float4* ksrc = (const float4*)(kb + (size_t)krow * kD + kc0);
#pragma unroll
    for (int g = 0; g < 4; ++g) kbuf[g] = ksrc[g];
#pragma unroll
    for (int kk = 0; kk < 4; ++kk)
      vbuf[kk] = *(const float4*)(vb + (size_t)(vkey4 + kk) * kD + vd0);
  }

  for (int kt = 0; kt < kS / 64; ++kt) {
    __syncthreads();  // previous tile's compute done; LDS K/V reusable
    // ---- stage K (row-major f16) ----
#pragma unroll
    for (int g = 0; g < 4; ++g) {
      float t[4] = {kbuf[g].x, kbuf[g].y, kbuf[g].z, kbuf[g].w};
      H4 hk;
#pragma unroll
      for (int j = 0; j < 4; ++j) hk.h[j] = (_Float16)t[j];
      *(uint2*)&sK[krow][kc0 + g * 4] = hk.u2;
    }
    // ---- stage V transposed via in-register 4x4 sub-transpose ----
    {
      float tv[4][4];
#pragma unroll
      for (int kk = 0; kk < 4; ++kk) {
        tv[kk][0] = vbuf[kk].x; tv[kk][1] = vbuf[kk].y;
        tv[kk][2] = vbuf[kk].z; tv[kk][3] = vbuf[kk].w;
      }
#pragma unroll
      for (int j = 0; j < 4; ++j) {
        H4 hv;
#pragma unroll
        for (int kk = 0; kk < 4; ++kk) hv.h[kk] = (_Float16)tv[kk][j];
        *(uint2*)&sVt[vd0 + j][vkey4] = hv.u2;
      }
    }
    // ---- prefetch next tile ----
    {
      const int ktn = (kt + 1) & 15;
      const float4* ksrc =
          (const float4*)(kb + (size_t)(ktn * 64 + krow) * kD + kc0);
#pragma unroll
      for (int g = 0; g < 4; ++g) kbuf[g] = ksrc[g];
#pragma unroll
      for (int kk = 0; kk < 4; ++kk)
        vbuf[kk] =
            *(const float4*)(vb + (size_t)(ktn * 64 + vkey4 + kk) * kD + vd0);
    }
    __syncthreads();

    // ---- two passes of 2 q-groups each (caps S live range at 32 VGPRs) ----
#pragma unroll
    for (int h = 0; h < 2; ++h) {
      // S^T = K·Q^T: per mt one pair of fk reads feeds both groups of the pass.
      floatx4 S[2][4];  // [g][mt]; score(key=mt*16+quad*4+reg, qrow=(h2+g)*16+r)
      __builtin_amdgcn_s_setprio(1);
#pragma unroll
      for (int mt = 0; mt < 4; ++mt) {
        half8 fk0 = *(const half8*)&sK[mt * 16 + r][0 * 32 + quad * 8];
        half8 fk1 = *(const half8*)&sK[mt * 16 + r][1 * 32 + quad * 8];
#pragma unroll
        for (int g = 0; g < 2; ++g) {
          const int ntq = h * 2 + g;
          floatx4 ah = {0.f, 0.f, 0.f, 0.f}, al = {0.f, 0.f, 0.f, 0.f};
          ah = __builtin_amdgcn_mfma_f32_16x16x32_f16(fk0, fqh[ntq][0], ah, 0, 0, 0);
          ah = __builtin_amdgcn_mfma_f32_16x16x32_f16(fk1, fqh[ntq][1], ah, 0, 0, 0);
          al = __builtin_amdgcn_mfma_f32_16x16x32_f16(fk0, fql[ntq][0], al, 0, 0, 0);
          al = __builtin_amdgcn_mfma_f32_16x16x32_f16(fk1, fql[ntq][1], al, 0, 0, 0);
          S[g][mt] = ah + al;
        }
      }
      __builtin_amdgcn_s_setprio(0);

      // online softmax with deferred rescale (T13)
      float tm[2];
#pragma unroll
      for (int g = 0; g < 2; ++g) {
        float t = -INFINITY;
#pragma unroll
        for (int mt = 0; mt < 4; ++mt)
#pragma unroll
          for (int j = 0; j < 4; ++j) t = fmaxf(t, S[g][mt][j]);
        t = fmaxf(t, __shfl_xor(t, 16, 64));
        t = fmaxf(t, __shfl_xor(t, 32, 64));
        tm[g] = t;
      }
      const unsigned long long need =
          __ballot(tm[0] > m_i[h * 2] + kThr || tm[1] > m_i[h * 2 + 1] + kThr);
      if (need) {
        float alpha[2];
#pragma unroll
        for (int g = 0; g < 2; ++g) {
          const int ntq = h * 2 + g;
          const float mn = fmaxf(m_i[ntq], tm[g]);
          alpha[g] = fast_exp2(m_i[ntq] - mn);  // first tile: exp2(-inf)=0
          m_i[ntq] = mn;
          l_i[ntq] *= alpha[g];
        }
        // rescale O rows of this pass's groups (row = ntq*16 + quad*4 + j)
#pragma unroll
        for (int g = 0; g < 2; ++g) {
          const int mtq = h * 2 + g;
#pragma unroll
          for (int j = 0; j < 4; ++j) {
            const float a = __shfl(alpha[g], quad * 4 + j, 64);
#pragma unroll
            for (int nd = 0; nd < 4; ++nd) O[mtq][nd][j] *= a;
          }
        }
      }
      // P = exp2(S - m) with (possibly stale) m; pack to f16; accumulate l.
#pragma unroll
      for (int g = 0; g < 2; ++g) {
        const int ntq = h * 2 + g;
        float rs = 0.f;
#pragma unroll
        for (int mt = 0; mt < 4; ++mt) {
          H4 hp;
#pragma unroll
          for (int j = 0; j < 4; ++j) {
            float pj = fast_exp2(S[g][mt][j] - m_i[ntq]);
            rs += pj;
            hp.h[j] = (_Float16)pj;
          }
          *(uint2*)&sP[w * 64 + ntq * 16 + r][mt * 16 + quad * 4] = hp.u2;
        }
        rs += __shfl_xor(rs, 16, 64);
        rs += __shfl_xor(rs, 32, 64);
        l_i[ntq] += rs;
      }
    }

    // ---- O += P·V: each fv read shared across FOUR q-row groups ----
    __builtin_amdgcn_s_setprio(1);
#pragma unroll
    for (int ks = 0; ks < 2; ++ks) {
      half8 fp[4];
#pragma unroll
      for (int mtq = 0; mtq < 4; ++mtq)
        fp[mtq] = *(const half8*)&sP[w * 64 + mtq * 16 + r][ks * 32 + quad * 8];
#pragma unroll
      for (int nd = 0; nd < 4; ++nd) {
        half8 fv = *(const half8*)&sVt[nd * 16 + r][ks * 32 + quad * 8];
#pragma unroll
        for (int mtq = 0; mtq < 4; ++mtq)
          O[mtq][nd] =
              __builtin_amdgcn_mfma_f32_16x16x32_f16(fp[mtq], fv, O[mtq][nd], 0, 0, 0);
      }
    }
    __builtin_amdgcn_s_setprio(0);
  }

  // ---- epilogue: out[qrow][dim] = O / l ----
#pragma unroll
  for (int mtq = 0; mtq < 4; ++mtq)
#pragma unroll
    for (int j = 0; j < 4; ++j) {
      const float lrow = __shfl(l_i[mtq], quad * 4 + j, 64);
      const float linv = fast_rcp(lrow);
      float* dst =
          ob + (size_t)(qbase + w * 64 + mtq * 16 + quad * 4 + j) * kD + r;
#pragma unroll
      for (int nd = 0; nd < 4; ++nd) dst[nd * 16] = O[mtq][nd][j] * linv;
    }
}

}  // namespace

extern "C" void kernel_launch(void* const* d_in, const int* in_sizes, int n_in,
                              void* d_out, int out_size, void* d_ws, size_t ws_size,
                              hipStream_t stream) {
  const float* q = (const float*)d_in[0];
  const float* k = (const float*)d_in[1];
  const float* v = (const float*)d_in[2];
  float* out = (float*)d_out;

  fa_mfma_kernel<<<dim3(512), 256, 0, stream>>>(q, k, v, out);
}